// Round 13
// baseline (321.861 us; speedup 1.0000x reference)
//
#include <hip/hip_runtime.h>
#include <hip/hip_fp16.h>
#include <hip/hip_bf16.h>

// Problem constants (from reference)
constexpr int NN   = 10000;  // N_NODES
constexpr int DMAX = 128;    // D_MAX
constexpr int ROWS = 128;    // B*F = 2*64 values per node
constexpr int JL   = 64;     // LDS-staged row cap (16 KB -> 10 blocks/CU)

// ---------------------------------------------------------------------------
// Kernel 1: transpose+convert x (f32, 128 x 10000) -> xTh (fp16, 10000 x 128).
// fp16 keys (r12, verified absmax 0.0156 < tol): table is 2.56 MB -> L2-
// resident; selection picks an fp16-rounded data value, k=0 term stays f32.
// ---------------------------------------------------------------------------
__global__ __launch_bounds__(256) void transpose_kernel(
    const float* __restrict__ x, __half* __restrict__ xTh)
{
    __shared__ float tile[32][33];
    const int n0 = blockIdx.x * 32;
    const int r0 = blockIdx.y * 32;
    const int tx = threadIdx.x;   // 0..31
    const int ty = threadIdx.y;   // 0..7
    #pragma unroll
    for (int i = 0; i < 32; i += 8) {
        const int r = r0 + ty + i;
        const int n = n0 + tx;
        if (n < NN) tile[ty + i][tx] = x[(size_t)r * NN + n];
    }
    __syncthreads();
    #pragma unroll
    for (int i = 0; i < 32; i += 8) {
        const int n = n0 + ty + i;
        const int r = r0 + tx;
        if (n < NN) xTh[(size_t)n * ROWS + r] = __float2half(tile[tx][ty + i]);
    }
}

// ---------------------------------------------------------------------------
// Exact median, ONE lane per column (r9/r11/r12 champion structure), with the
// ROUND-13 change: the first min(ln,64) neighbor rows are staged ONCE into
// LDS (fp16, [j][col] layout: stage writes and pass reads are both 2-lanes-
// per-bank = conflict-free), and every quickselect pass re-streams from LDS
// at static immediate offsets (j*256) instead of paying ~200-cyc L2 latency
// per element (r12 lesson: FETCH collapsed but dur didn't -> latency-bound).
// Rows beyond 64 (only when ln>64, ~12% of elements) stream from L2 as in r12.
//
// Selection logic unchanged (proven r2-r12):
//   cheap passes: c = #{v<=m} (2 VALU/elem); snap passes also track
//   mx=max{v<=m}, mn=min{v>m}; dosnap = ballot(need_snap) || pass>=6.
//   c==mid+1 -> x=mx ; c==mid -> x=mn ; lo>=hi -> x=lo  (duplicate-safe)
//   snap: c>mid+1 -> hi=mx ; c<mid -> lo=mn  (snaps to data, strict shrink)
//   cheap: c>mid+1 -> hi=m ; c<mid -> lo=m
//   secant pivot on empirical CDF, clamped to bracket; mN>=hi -> mN=lo guard.
// ---------------------------------------------------------------------------
__device__ __forceinline__ float stream_median_lds(
    const __half (*__restrict__ keys)[ROWS],
    const __half* __restrict__ xTh,
    const int* __restrict__ idxp,
    int ln, int jl, int col)
{
    const float INF  = 1e30f;
    const int   mid  = (ln - 1) >> 1;
    const float midf = (float)mid + 0.5f;
    const float invs = 1.0f / (0.4f * (float)ln);   // Newton slope (N(0,1) pdf)
    float lo = -64.f, hi = 64.f, m = 0.f, x = 0.f;  // |data| < 10 << 64
    float mp = 0.f, cpf = 0.f;
    bool active = true, need_snap = false, have_prev = false;
    int  pass = 0;

    while (__ballot(active) != 0ull) {
        const bool dosnap = (pass >= 6) || (__ballot(need_snap) != 0ull); // uniform

        int   c  = 0;
        float mx = -INF, mn = INF;
        if (dosnap) {
            #pragma unroll 4
            for (int j = 0; j < jl; ++j) {          // LDS part (uniform trips)
                const float v  = __half2float(keys[j][col]);
                const bool  le = v <= m;
                c  += le ? 1 : 0;
                mx  = le ? fmaxf(mx, v) : mx;
                mn  = le ? mn : fminf(mn, v);
            }
            for (int j = jl; j < ln; ++j) {         // L2 overflow (ln>64 only)
                const float v  = __half2float(xTh[(idxp[j] << 7) + col]);
                const bool  le = v <= m;
                c  += le ? 1 : 0;
                mx  = le ? fmaxf(mx, v) : mx;
                mn  = le ? mn : fminf(mn, v);
            }
        } else {
            #pragma unroll 4
            for (int j = 0; j < jl; ++j)
                c += (__half2float(keys[j][col]) <= m) ? 1 : 0;
            for (int j = jl; j < ln; ++j)
                c += (__half2float(xTh[(idxp[j] << 7) + col]) <= m) ? 1 : 0;
        }

        if (active) {
            const float fc = (float)c;
            if (dosnap) {
                need_snap = false;
                if      (c == mid + 1) { x = mx; active = false; }
                else if (c == mid)     { x = mn; active = false; }
                else {
                    if (c > mid + 1) hi = mx; else lo = mn;     // snap: strict shrink
                    if (lo >= hi) { x = lo; active = false; }
                    else {
                        const float dd = fc - cpf;
                        float mN = (have_prev && dd != 0.f)
                                 ? m + (midf - fc) * (m - mp) * __builtin_amdgcn_rcpf(dd)
                                 : m + (midf - fc) * invs;
                        mp = m; cpf = fc; have_prev = true;
                        if (!(mN > lo && mN < hi)) mN = 0.5f * (lo + hi);
                        if (mN >= hi) mN = lo;                  // termination guard
                        m = mN;
                    }
                }
            } else {
                if (c == mid + 1 || c == mid) {
                    need_snap = true;                // redo same pivot with snap
                } else {
                    if (c > mid + 1) hi = m; else lo = m;
                    const float dd = fc - cpf;
                    float mN = (have_prev && dd != 0.f)
                             ? m + (midf - fc) * (m - mp) * __builtin_amdgcn_rcpf(dd)
                             : m + (midf - fc) * invs;
                    mp = m; cpf = fc; have_prev = true;
                    if (!(mN > lo && mN < hi)) mN = 0.5f * (lo + hi);
                    if (mN >= hi) mN = lo;
                    m = mN;
                }
            }
        }
        ++pass;
    }
    return x;
}

// ---------------------------------------------------------------------------
// Kernel 2: one block (128 thr = 2 waves) per node; thread t owns column t.
// Per hop: barrier -> stage min(ln,64) rows into LDS (coalesced 256B global
// reads, conflict-free ds_writes) -> barrier -> selection (all-LDS passes).
// 16 KB LDS -> 10 blocks/CU -> ~20 waves/CU (occupancy preserved vs r12).
// ---------------------------------------------------------------------------
__global__ __launch_bounds__(128, 8) void median_combine(
    const __half* __restrict__ xTh, const float* __restrict__ xorig,
    const float* __restrict__ w,
    const int* __restrict__ nidx, const int* __restrict__ nlen,
    float* __restrict__ out)
{
    __shared__ __half keys[JL][ROWS];   // 16 KB
    const int t = threadIdx.x;          // column 0..127  (= b*64+f)
    const int n = blockIdx.x;

    float medk[2];
    #pragma unroll
    for (int k = 0; k < 2; ++k) {
        const int ln = nlen[k * NN + n];                     // wave-uniform
        const int* idxp = nidx + ((size_t)k * NN + n) * DMAX;
        const int jl = min(ln, JL);

        __syncthreads();   // prior hop's readers done before overwrite
        #pragma unroll 4
        for (int j = 0; j < jl; ++j)
            keys[j][t] = xTh[(idxp[j] << 7) + t];
        __syncthreads();

        medk[k] = stream_median_lds(keys, xTh, idxp, ln, jl, t);
    }

    const float xv = xorig[(size_t)t * NN + n];              // exact f32 term
    out[(size_t)t * NN + n] = w[0] * xv + w[1] * medk[0] + w[2] * medk[1];
}

extern "C" void kernel_launch(void* const* d_in, const int* in_sizes, int n_in,
                              void* d_out, int out_size, void* d_ws, size_t ws_size,
                              hipStream_t stream) {
    const float* x    = (const float*)d_in[0];   // (2,64,10000) f32
    const float* w    = (const float*)d_in[1];   // (1,3) f32
    const int*   nidx = (const int*)d_in[2];     // (2,10000,128) i32
    const int*   nlen = (const int*)d_in[3];     // (2,10000) i32
    float* out = (float*)d_out;                  // (2,64,10000) f32
    __half* xTh = (__half*)d_ws;                 // 10000*128 fp16 = 2.56 MB scratch

    dim3 tb(32, 8);
    dim3 tg((NN + 31) / 32, ROWS / 32);
    transpose_kernel<<<tg, tb, 0, stream>>>(x, xTh);
    median_combine<<<NN, 128, 0, stream>>>(xTh, x, w, nidx, nlen, out);
}